// Round 1
// baseline (19.329 us; speedup 1.0000x reference)
//
#include <hip/hip_runtime.h>

// QuanvolutionFilter: 4-qubit RY+CNOT circuit on every 2x2 patch.
// State = 16 real amplitudes, kept entirely in VGPRs (fully unrolled).
// Qubit k maps to bit (3-k) of the state index: a=bit3, b=bit2, c=bit1, d=bit0.

__global__ __launch_bounds__(256) void quanv_kernel(
    const float* __restrict__ x,   // [64,1,256,256]
    const float* __restrict__ w,   // [2,4]
    float* __restrict__ out,       // [N,4] flat
    int npatch)
{
    // Per-block: compute weight trig once (uniform), broadcast via LDS.
    __shared__ float wtrig[16];  // [layer][{cos(4), sin(4)}]
    if (threadIdx.x < 8) {
        int l = threadIdx.x >> 2, q = threadIdx.x & 3;
        float h = w[threadIdx.x] * 0.5f;
        float sn, cs;
        __sincosf(h, &sn, &cs);
        wtrig[l * 8 + q]     = cs;
        wtrig[l * 8 + 4 + q] = sn;
    }
    __syncthreads();

    int n = blockIdx.x * blockDim.x + threadIdx.x;
    if (n >= npatch) return;

    int b   = n >> 14;        // / (128*128)
    int rem = n & 16383;
    int r   = rem >> 7;       // patch row
    int c   = rem & 127;      // patch col

    // Coalesced: thread reads float2 from each of the 2 image rows.
    const float2* row0 = reinterpret_cast<const float2*>(x + (size_t)b * 65536 + (size_t)(2 * r) * 256);
    const float2* row1 = reinterpret_cast<const float2*>(x + (size_t)b * 65536 + (size_t)(2 * r + 1) * 256);
    float2 t = row0[c];   // ang0, ang1
    float2 u = row1[c];   // ang2, ang3

    float cq[4], sq[4];
    __sincosf(t.x * 0.5f, &sq[0], &cq[0]);
    __sincosf(t.y * 0.5f, &sq[1], &cq[1]);
    __sincosf(u.x * 0.5f, &sq[2], &cq[2]);
    __sincosf(u.y * 0.5f, &sq[3], &cq[3]);

    // Initial rank-1 product state.
    float st[16];
    #pragma unroll
    for (int i = 0; i < 16; ++i) {
        float va = (i & 8) ? sq[0] : cq[0];
        float vb = (i & 4) ? sq[1] : cq[1];
        float vc = (i & 2) ? sq[2] : cq[2];
        float vd = (i & 1) ? sq[3] : cq[3];
        st[i] = va * vb * vc * vd;
    }

    #pragma unroll
    for (int l = 0; l < 2; ++l) {
        // RY(weights[l][q]) on each wire q (bit = 8 >> q).
        #pragma unroll
        for (int q = 0; q < 4; ++q) {
            float cw = wtrig[l * 8 + q];
            float sw = wtrig[l * 8 + 4 + q];
            const int bit = 8 >> q;
            #pragma unroll
            for (int i = 0; i < 16; ++i) {
                if (!(i & bit)) {
                    const int j = i | bit;
                    float a0 = st[i], a1 = st[j];
                    st[i] = cw * a0 - sw * a1;   // new0 = c*o0 - s*o1
                    st[j] = sw * a0 + cw * a1;   // new1 = s*o0 + c*o1
                }
            }
        }
        // CNOT(0,1): control a (bit3), flip b (bit2).
        #pragma unroll
        for (int xlow = 0; xlow < 4; ++xlow) {
            float tmp = st[8 + xlow];
            st[8 + xlow]  = st[12 + xlow];
            st[12 + xlow] = tmp;
        }
        // CNOT(2,3): control c (bit1), flip d (bit0).
        #pragma unroll
        for (int hi = 0; hi < 4; ++hi) {
            const int base = hi << 2;
            float tmp = st[base + 2];
            st[base + 2] = st[base + 3];
            st[base + 3] = tmp;
        }
    }

    // PauliZ expectations.
    float z0 = 0.f, z1 = 0.f, z2 = 0.f, z3 = 0.f;
    #pragma unroll
    for (int i = 0; i < 16; ++i) {
        float p = st[i] * st[i];
        z0 += (i & 8) ? -p : p;
        z1 += (i & 4) ? -p : p;
        z2 += (i & 2) ? -p : p;
        z3 += (i & 1) ? -p : p;
    }

    reinterpret_cast<float4*>(out)[n] = make_float4(z0, z1, z2, z3);
}

extern "C" void kernel_launch(void* const* d_in, const int* in_sizes, int n_in,
                              void* d_out, int out_size, void* d_ws, size_t ws_size,
                              hipStream_t stream) {
    const float* x = (const float*)d_in[0];
    const float* w = (const float*)d_in[1];
    float* out = (float*)d_out;
    int npatch = out_size / 4;  // 1,048,576
    int threads = 256;
    int blocks = (npatch + threads - 1) / threads;
    quanv_kernel<<<blocks, threads, 0, stream>>>(x, w, out, npatch);
}

// Round 2
// 11.496 us; speedup vs baseline: 1.6814x; 1.6814x over previous
//
#include <hip/hip_runtime.h>

// QuanvolutionFilter: 4-qubit RY+CNOT circuit on every 2x2 patch.
//
// Algebraic structure exploited:
//  - Layer-1 RY(w0q) fuses into the encoding angles: RY(w)RY(x)|0> = RY(x+w)|0>.
//  - Only CNOT(0,1) and CNOT(2,3) exist -> qubit blocks {0,1} and {2,3} never
//    entangle with each other. State = (4-amp AB block) x (4-amp CD block)
//    throughout; CNOTs are index permutations (free), layer-2 RYs act on
//    4-vectors, and Z expectations factor: z0 = zA*Scd, z1 = zB*Scd,
//    z2 = Sab*zC, z3 = Sab*zD.
//  - Native v_sin/v_cos (angles < 3.7 rad, err ~1e-6 << 2e-2 threshold).

__device__ __forceinline__ void block2q(float hA, float hB, float cw0, float sw0,
                                        float cw1, float sw1,
                                        float& z_hi, float& z_lo, float& S) {
    float cA = __cosf(hA), sA = __sinf(hA);
    float cB = __cosf(hB), sB = __sinf(hB);
    // Outer product, with CNOT(hi,lo) folded in (row hi=1 swapped):
    float ab00 = cA * cB, ab01 = cA * sB;
    float ab10 = sA * sB, ab11 = sA * cB;   // swapped: AB1[1][b] = AB0[1][1-b]
    // Layer-2 RY on hi qubit (mixes first index):
    float t00 = cw0 * ab00 - sw0 * ab10;
    float t10 = sw0 * ab00 + cw0 * ab10;
    float t01 = cw0 * ab01 - sw0 * ab11;
    float t11 = sw0 * ab01 + cw0 * ab11;
    // Layer-2 RY on lo qubit (mixes second index):
    float u00 = cw1 * t00 - sw1 * t01;
    float u01 = sw1 * t00 + cw1 * t01;
    float u10 = cw1 * t10 - sw1 * t11;
    float u11 = sw1 * t10 + cw1 * t11;
    // Final CNOT folded into prob indexing: P[1][0]=u11^2, P[1][1]=u10^2.
    float p00 = u00 * u00, p01 = u01 * u01;
    float p10 = u11 * u11, p11 = u10 * u10;
    float s0 = p00 + p01, s1 = p10 + p11;
    z_hi = s0 - s1;                      // sign by hi qubit
    z_lo = (p00 - p01) + (p10 - p11);    // sign by lo qubit
    S    = s0 + s1;                      // block norm (~1)
}

__device__ __forceinline__ float4 patch_ev(float x0, float x1, float x2, float x3,
                                           const float* __restrict__ wls) {
    // wls: [c1(4), s1(4), h0(4)]  (layer-2 cos/sin, layer-1 half-weights)
    float zA, zB, Sab, zC, zD, Scd;
    block2q(x0 * 0.5f + wls[8],  x1 * 0.5f + wls[9],
            wls[0], wls[4], wls[1], wls[5], zA, zB, Sab);
    block2q(x2 * 0.5f + wls[10], x3 * 0.5f + wls[11],
            wls[2], wls[6], wls[3], wls[7], zC, zD, Scd);
    return make_float4(zA * Scd, zB * Scd, Sab * zC, Sab * zD);
}

__global__ __launch_bounds__(256) void quanv_kernel(
    const float* __restrict__ x,   // [64,1,256,256]
    const float* __restrict__ w,   // [2,4]
    float* __restrict__ out,       // [N,4] flat
    int npair)                     // npatch/2
{
    __shared__ float wls[12];
    if (threadIdx.x < 4) {
        int q = threadIdx.x;
        float h1 = w[4 + q] * 0.5f;
        wls[q]     = __cosf(h1);
        wls[4 + q] = __sinf(h1);
        wls[8 + q] = w[q] * 0.5f;
    }
    __syncthreads();

    int t = blockIdx.x * blockDim.x + threadIdx.x;
    if (t >= npair) return;

    int b   = t >> 13;        // / (128 rows * 64 pairs)
    int rem = t & 8191;
    int r   = rem >> 6;       // patch row
    int u   = rem & 63;       // pair-column (covers image cols 4u..4u+3)

    const float* base = x + (size_t)b * 65536 + (size_t)(2 * r) * 256;
    float4 f0 = reinterpret_cast<const float4*>(base)[u];         // image row 2r
    float4 f1 = reinterpret_cast<const float4*>(base + 256)[u];   // image row 2r+1

    float4 ev0 = patch_ev(f0.x, f0.y, f1.x, f1.y, wls);
    float4 ev1 = patch_ev(f0.z, f0.w, f1.z, f1.w, wls);

    float4* o = reinterpret_cast<float4*>(out);
    o[2 * t]     = ev0;
    o[2 * t + 1] = ev1;
}

extern "C" void kernel_launch(void* const* d_in, const int* in_sizes, int n_in,
                              void* d_out, int out_size, void* d_ws, size_t ws_size,
                              hipStream_t stream) {
    const float* x = (const float*)d_in[0];
    const float* w = (const float*)d_in[1];
    float* out = (float*)d_out;
    int npair = out_size / 8;  // 524,288 threads, 2 patches each
    int threads = 256;
    int blocks = (npair + threads - 1) / threads;
    quanv_kernel<<<blocks, threads, 0, stream>>>(x, w, out, npair);
}